// Round 5
// baseline (584.080 us; speedup 1.0000x reference)
//
#include <hip/hip_runtime.h>
#include <hip/hip_bf16.h>

// Problem constants (T=2048, B=8, C=512, O=512, RD=64, NE=8, tau=1, commit=0.1)
// All I/O float32. Single fused GEMM over K'=9*512: resp folded into A at
// staging (bf16). Round-5: software-pipelined K-loop, double-buffered LDS,
// one barrier/iter, 2-deep x register prefetch (round-4 was barrier-latency
// serialized: 2930 cyc/block-iter vs ~960 pipe demand).
#define NROWS 16384
#define CC 512
#define OO 512
#define RDIM 64
#define NE 8
#define NEXP 9            // 8 experts + bias_w as expert 8 (scale 1.0)
#define KITER 144         // 9 experts * 16 k-chunks of 32
#define COMMIT_SCALE 0.1f
#define LOG2PI_TERM 58.81206612509905f   // (RD/2)*log(2*pi*tau), tau=1

typedef __attribute__((ext_vector_type(8))) short short8;
typedef __attribute__((ext_vector_type(4))) float f32x4;

__device__ __forceinline__ unsigned short f2bf(float f) {
  unsigned int u = __float_as_uint(f);
  u += 0x7fffu + ((u >> 16) & 1u);   // round-to-nearest-even
  return (unsigned short)(u >> 16);
}
__device__ __forceinline__ unsigned int pk2(float a, float b) {
  return ((unsigned int)f2bf(a)) | (((unsigned int)f2bf(b)) << 16);
}

__device__ __forceinline__ void gl_lds16(const unsigned short* g, unsigned short* l) {
  __builtin_amdgcn_global_load_lds(
      (const __attribute__((address_space(1))) void*)g,
      (__attribute__((address_space(3))) void*)l, 16, 0, 0);
}

// ---------------------------------------------------------------------------
// Kernel 0: f32->bf16 copy of [pw_w ; bias_w] -> wb; transpose map_w -> wT4.
// ---------------------------------------------------------------------------
#define P4 524288u    // pw_w float4 count   (2097152 / 4)
#define B4 65536u     // bias_w float4 count (262144 / 4)
#define NCV ((P4 + B4) / 256u)        // 2304 convert blocks
#define TB 128u                        // 32768 map_w elems / 256

__global__ __launch_bounds__(256) void k_prep(
    const float* __restrict__ pw, const float* __restrict__ bw,
    const float* __restrict__ mw,
    unsigned short* __restrict__ wb, float* __restrict__ wT4)
{
  unsigned int b = blockIdx.x;
  if (b >= NCV) {   // map_w transpose: i indexes map_w[j*512+c]
    unsigned int i = (b - NCV) * 256 + threadIdx.x;
    unsigned int j = i >> 9, c = i & 511u;
    wT4[((c >> 2) << 8) + (j << 2) + (c & 3u)] = mw[i];
    return;
  }
  unsigned int i = b * 256 + threadIdx.x;   // float4 index into [pw|bw]
  const float* src = (i < P4) ? (pw + (size_t)i * 4)
                              : (bw + (size_t)(i - P4) * 4);
  unsigned short* dst = wb + (size_t)i * 4;
  float4 v = *(const float4*)src;
  ushort4 o;
  o.x = f2bf(v.x); o.y = f2bf(v.y); o.z = f2bf(v.z); o.w = f2bf(v.w);
  *(ushort4*)dst = o;
}

// ---------------------------------------------------------------------------
// Kernel 1: GMM responsibilities + loss (pure f32).
// ---------------------------------------------------------------------------
__global__ __launch_bounds__(256) void k_assign(
    const float* __restrict__ x,      // [N, C]
    const float* __restrict__ wT4,    // [C/4, 64, 4] transposed map_w
    const float* __restrict__ map_b,  // [RD]
    const float* __restrict__ cent,   // [NE, RD]
    const float* __restrict__ prior,  // [NE]
    float* __restrict__ resp_out,     // [N, NE] f32 (ws)
    float* __restrict__ loss_acc)     // [1] f32 (ws)
{
  __shared__ float lsum[4];
  const int tid  = threadIdx.x;
  const int wid  = tid >> 6;
  const int lane = tid & 63;
  const int row0 = blockIdx.x * 16 + wid * 4;

  const float* xr0 = x + (size_t)row0 * CC;
  float acc[4] = {0.f, 0.f, 0.f, 0.f};
  #pragma unroll 4
  for (int c0 = 0; c0 < CC; c0 += 4) {
    float4 wv = *(const float4*)&wT4[(c0 << 6) + (lane << 2)];  // coalesced
    #pragma unroll
    for (int r = 0; r < 4; ++r) {
      float4 xv = *(const float4*)(xr0 + r * CC + c0);          // wave-uniform
      acc[r] += xv.x * wv.x + xv.y * wv.y + xv.z * wv.z + xv.w * wv.w;
    }
  }
  const float mb = map_b[lane];
  float kk[4] = {acc[0] + mb, acc[1] + mb, acc[2] + mb, acc[3] + mb};

  float ce[8], c2[8], lp[8];
  #pragma unroll
  for (int e = 0; e < 8; ++e) {
    ce[e] = cent[e * RDIM + lane];
    float v = ce[e] * ce[e];
    #pragma unroll
    for (int off = 32; off; off >>= 1) v += __shfl_xor(v, off, 64);
    c2[e] = v;
    lp[e] = __logf(prior[e]);
  }

  float dsum = 0.f;
  #pragma unroll
  for (int r = 0; r < 4; ++r) {
    float k = kk[r];
    float v[9];
    v[0] = k * k;
    #pragma unroll
    for (int e = 0; e < 8; ++e) v[e + 1] = k * ce[e];
    #pragma unroll
    for (int off = 32; off; off >>= 1) {
      #pragma unroll
      for (int q = 0; q < 9; ++q) v[q] += __shfl_xor(v[q], off, 64);
    }
    float lr[8], mx = -3.4e38f;
    #pragma unroll
    for (int e = 0; e < 8; ++e) {
      float d2 = v[0] + c2[e] - 2.f * v[e + 1];
      lr[e] = -0.5f * d2 - LOG2PI_TERM + lp[e];
      mx = fmaxf(mx, lr[e]);
    }
    float s = 0.f;
    #pragma unroll
    for (int e = 0; e < 8; ++e) s += __expf(lr[e] - mx);
    float denom = mx + __logf(s);
    dsum += denom;
    float myv = 0.f;
    #pragma unroll
    for (int e = 0; e < 8; ++e) {
      float re = __expf(lr[e] - denom);
      myv = (lane == e) ? re : myv;
    }
    if (lane < 8) resp_out[(size_t)(row0 + r) * NE + lane] = myv;
  }
  if (lane == 0) lsum[wid] = dsum;
  __syncthreads();
  if (tid == 0) {
    float t = lsum[0] + lsum[1] + lsum[2] + lsum[3];
    atomicAdd(loss_acc, -COMMIT_SCALE * t);
  }
}

// ---------------------------------------------------------------------------
// Kernel 2: y[m,o] = sum_e sum_k (resp[m,e]*x[m,k]) * W_e[o,k] + bias_b[o].
// Software-pipelined: dbuf LDS (A padded-40 via ds_write, B unpadded via
// global_load_lds w/ XOR swizzle), one barrier/iter, x prefetched 2 deep.
// ---------------------------------------------------------------------------
__global__ __launch_bounds__(256, 2) void k_moe(
    const float* __restrict__ x,             // [N, C] f32
    const unsigned short* __restrict__ wb,   // [9, O, C] bf16 (ws)
    const float* __restrict__ bb,            // [O] f32
    const float* __restrict__ resp,          // [N, NE] f32 (ws)
    const float* __restrict__ loss_acc,      // [1] f32 (ws)
    float* __restrict__ out)                 // [N*O + 1] f32
{
  __shared__ unsigned short aT[2][128 * 40];   // padded stride 40
  __shared__ unsigned short bT[2][128 * 32];   // unpadded (gl_lds)
  __shared__ float sc[NEXP * 128];

  const int tid = threadIdx.x;
  const int m0 = blockIdx.x * 128;
  const int o0 = blockIdx.y * 128;

  for (int idx = tid; idx < 128 * NE; idx += 256) {
    int r = idx >> 3, e = idx & 7;
    sc[e * 128 + r] = resp[(size_t)(m0 + r) * NE + e];
  }
  if (tid < 128) sc[8 * 128 + tid] = 1.0f;

  const int lane = tid & 63;
  const int wid = tid >> 6;
  const int wm = (wid & 1) * 64;
  const int wn = (wid >> 1) * 64;
  const int fr = lane & 15;
  const int fq = lane >> 4;

  // A staging: thread -> row srow, 16 k at scol
  const int srow = tid >> 1;
  const int scol = (tid & 1) * 16;
  const float4* xbase = (const float4*)(x + (size_t)(m0 + srow) * CC) + (tid & 1) * 4;

  // B staging via gl_lds: lane l -> row l>>2, chunk pos l&3, double-XOR swizzle
  const int srB = lane >> 2;
  const int gchunk = (lane & 3) ^ (srB & 3) ^ ((srB >> 2) & 3);
  const size_t b_go = (size_t)(o0 + wid * 32 + srB) * CC + gchunk * 8;
  const unsigned short* wbp = wb + b_go;
  const size_t row16 = (size_t)16 * CC;
  const int ldsB = wid * 1024;
  const int rchunkB = (fq ^ (fr & 3) ^ ((fr >> 2) & 3)) * 8;

  f32x4 zero4 = {0.f, 0.f, 0.f, 0.f};
  f32x4 acc[4][4];
  #pragma unroll
  for (int i = 0; i < 4; ++i)
    #pragma unroll
    for (int j = 0; j < 4; ++j) acc[i][j] = zero4;

  float4 xr[2][4];
  __syncthreads();   // sc visible

  // ---- prologue: x[0] -> regs, pack A[0], gl_lds B[0], x[1] -> regs ----
  #pragma unroll
  for (int t = 0; t < 4; ++t) xr[0][t] = xbase[t];
  {
    const float s = sc[srow];   // e=0
    uint4 w0, w1;
    w0.x = pk2(xr[0][0].x * s, xr[0][0].y * s); w0.y = pk2(xr[0][0].z * s, xr[0][0].w * s);
    w0.z = pk2(xr[0][1].x * s, xr[0][1].y * s); w0.w = pk2(xr[0][1].z * s, xr[0][1].w * s);
    w1.x = pk2(xr[0][2].x * s, xr[0][2].y * s); w1.y = pk2(xr[0][2].z * s, xr[0][2].w * s);
    w1.z = pk2(xr[0][3].x * s, xr[0][3].y * s); w1.w = pk2(xr[0][3].z * s, xr[0][3].w * s);
    *(uint4*)&aT[0][srow * 40 + scol]     = w0;
    *(uint4*)&aT[0][srow * 40 + scol + 8] = w1;
  }
  gl_lds16(wbp,         &bT[0][ldsB]);
  gl_lds16(wbp + row16, &bT[0][ldsB + 512]);
  #pragma unroll
  for (int t = 0; t < 4; ++t) xr[1][t] = xbase[8 + t];

  // ---- main loop: one barrier per iteration ----
  #pragma unroll 2
  for (int it = 0; it < KITER; ++it) {
    const int cur = it & 1, nxt = cur ^ 1;
    __syncthreads();   // A[it],B[it] staged; prev readers of buf `nxt` done

    short8 af[4], bfr[4];
    #pragma unroll
    for (int i = 0; i < 4; ++i)
      af[i] = *(const short8*)&aT[cur][(wm + i * 16 + fr) * 40 + fq * 8];
    #pragma unroll
    for (int j = 0; j < 4; ++j)
      bfr[j] = *(const short8*)&bT[cur][(wn + j * 16 + fr) * 32 + rchunkB];

    if (it < KITER - 1) {
      const int it1 = it + 1;
      const unsigned short* Bb = wbp + (size_t)(it1 >> 4) * (OO * CC) + (it1 & 15) * 32;
      gl_lds16(Bb,         &bT[nxt][ldsB]);
      gl_lds16(Bb + row16, &bT[nxt][ldsB + 512]);
      const float s = sc[(it1 >> 4) * 128 + srow];
      const float4 v0 = xr[it1 & 1][0], v1 = xr[it1 & 1][1];
      const float4 v2 = xr[it1 & 1][2], v3 = xr[it1 & 1][3];
      uint4 w0, w1;
      w0.x = pk2(v0.x * s, v0.y * s); w0.y = pk2(v0.z * s, v0.w * s);
      w0.z = pk2(v1.x * s, v1.y * s); w0.w = pk2(v1.z * s, v1.w * s);
      w1.x = pk2(v2.x * s, v2.y * s); w1.y = pk2(v2.z * s, v2.w * s);
      w1.z = pk2(v3.x * s, v3.y * s); w1.w = pk2(v3.z * s, v3.w * s);
      *(uint4*)&aT[nxt][srow * 40 + scol]     = w0;
      *(uint4*)&aT[nxt][srow * 40 + scol + 8] = w1;
      if (it < KITER - 2) {   // x[it+2] -> xr[cur]
        const int k2 = (it + 2) & 15;
        #pragma unroll
        for (int t = 0; t < 4; ++t) xr[cur][t] = xbase[k2 * 8 + t];
      }
    }

    #pragma unroll
    for (int i = 0; i < 4; ++i)
      #pragma unroll
      for (int j = 0; j < 4; ++j)
        acc[i][j] = __builtin_amdgcn_mfma_f32_16x16x32_bf16(af[i], bfr[j], acc[i][j], 0, 0, 0);
  }

  // epilogue: + bias_b, store f32
  #pragma unroll
  for (int j = 0; j < 4; ++j) {
    const int o = o0 + wn + j * 16 + fr;
    const float bias = bb[o];
    #pragma unroll
    for (int i = 0; i < 4; ++i) {
      #pragma unroll
      for (int r = 0; r < 4; ++r) {
        int m = m0 + wm + i * 16 + fq * 4 + r;
        out[(size_t)m * OO + o] = acc[i][j][r] + bias;
      }
    }
  }

  if (blockIdx.x == 0 && blockIdx.y == 0 && tid == 0)
    out[(size_t)NROWS * OO] = loss_acc[0];
}

extern "C" void kernel_launch(void* const* d_in, const int* in_sizes, int n_in,
                              void* d_out, int out_size, void* d_ws, size_t ws_size,
                              hipStream_t stream) {
  const float* x     = (const float*)d_in[0];
  // d_in[1] = key_feat (ignored by forward)
  const float* map_w = (const float*)d_in[2];
  const float* map_b = (const float*)d_in[3];
  const float* cent  = (const float*)d_in[4];
  const float* prior = (const float*)d_in[5];
  const float* pw    = (const float*)d_in[6];
  const float* bw    = (const float*)d_in[7];
  const float* bb    = (const float*)d_in[8];
  float* out = (float*)d_out;

  char* wsp = (char*)d_ws;
  float* resp = (float*)wsp;                              // 524288 B
  float* loss = (float*)(wsp + 524288);                   // 16 B slot
  unsigned short* wb = (unsigned short*)(wsp + 524304);   // 4718592 B
  float* wT4 = (float*)(wsp + 524304 + 4718592);          // 131072 B

  hipMemsetAsync(loss, 0, sizeof(float), stream);
  k_prep<<<dim3(NCV + TB), dim3(256), 0, stream>>>(pw, bw, map_w, wb, wT4);
  k_assign<<<dim3(NROWS / 16), dim3(256), 0, stream>>>(x, wT4, map_b, cent, prior, resp, loss);
  dim3 grid(NROWS / 128, OO / 128);
  k_moe<<<grid, dim3(256), 0, stream>>>(x, wb, bb, resp, loss, out);
}

// Round 6
// 368.706 us; speedup vs baseline: 1.5841x; 1.5841x over previous
//
#include <hip/hip_runtime.h>
#include <hip/hip_bf16.h>

// Problem constants (T=2048, B=8, C=512, O=512, RD=64, NE=8, tau=1, commit=0.1)
// All I/O float32. Single fused GEMM over K'=9*512: resp folded into A at
// staging (bf16). Round-6: 64x128 tile (1024 blocks -> 4 blocks/CU),
// static-register 1-deep x prefetch (round-5's dynamic-indexed array
// spilled: WRITE_SIZE 968MB), truncating bf16 pack. Single-buffered LDS,
// 2 barriers/iter (round-4 proven structure).
#define NROWS 16384
#define CC 512
#define OO 512
#define RDIM 64
#define NE 8
#define NEXP 9            // 8 experts + bias_w as expert 8 (scale 1.0)
#define COMMIT_SCALE 0.1f
#define LOG2PI_TERM 58.81206612509905f   // (RD/2)*log(2*pi*tau), tau=1

typedef __attribute__((ext_vector_type(8))) short short8;
typedef __attribute__((ext_vector_type(4))) float f32x4;

__device__ __forceinline__ unsigned short f2bf(float f) {
  unsigned int u = __float_as_uint(f);
  u += 0x7fffu + ((u >> 16) & 1u);   // round-to-nearest-even
  return (unsigned short)(u >> 16);
}
// truncating pack: [hi16(b) | hi16(a)] — 1 ulp worse than RNE, threshold is 3788
__device__ __forceinline__ unsigned int pkt(float a, float b) {
  return (__float_as_uint(b) & 0xffff0000u) | (__float_as_uint(a) >> 16);
}

__device__ __forceinline__ void gl_lds16(const unsigned short* g, unsigned short* l) {
  __builtin_amdgcn_global_load_lds(
      (const __attribute__((address_space(1))) void*)g,
      (__attribute__((address_space(3))) void*)l, 16, 0, 0);
}

// ---------------------------------------------------------------------------
// Kernel 0: f32->bf16 copy of [pw_w ; bias_w] -> wb; transpose map_w -> wT4.
// ---------------------------------------------------------------------------
#define P4 524288u    // pw_w float4 count   (2097152 / 4)
#define B4 65536u     // bias_w float4 count (262144 / 4)
#define NCV ((P4 + B4) / 256u)        // 2304 convert blocks
#define TB 128u                        // 32768 map_w elems / 256

__global__ __launch_bounds__(256) void k_prep(
    const float* __restrict__ pw, const float* __restrict__ bw,
    const float* __restrict__ mw,
    unsigned short* __restrict__ wb, float* __restrict__ wT4)
{
  unsigned int b = blockIdx.x;
  if (b >= NCV) {   // map_w transpose: i indexes map_w[j*512+c]
    unsigned int i = (b - NCV) * 256 + threadIdx.x;
    unsigned int j = i >> 9, c = i & 511u;
    wT4[((c >> 2) << 8) + (j << 2) + (c & 3u)] = mw[i];
    return;
  }
  unsigned int i = b * 256 + threadIdx.x;   // float4 index into [pw|bw]
  const float* src = (i < P4) ? (pw + (size_t)i * 4)
                              : (bw + (size_t)(i - P4) * 4);
  unsigned short* dst = wb + (size_t)i * 4;
  float4 v = *(const float4*)src;
  ushort4 o;
  o.x = f2bf(v.x); o.y = f2bf(v.y); o.z = f2bf(v.z); o.w = f2bf(v.w);
  *(ushort4*)dst = o;
}

// ---------------------------------------------------------------------------
// Kernel 1: GMM responsibilities + loss (pure f32).
// ---------------------------------------------------------------------------
__global__ __launch_bounds__(256) void k_assign(
    const float* __restrict__ x,      // [N, C]
    const float* __restrict__ wT4,    // [C/4, 64, 4] transposed map_w
    const float* __restrict__ map_b,  // [RD]
    const float* __restrict__ cent,   // [NE, RD]
    const float* __restrict__ prior,  // [NE]
    float* __restrict__ resp_out,     // [N, NE] f32 (ws)
    float* __restrict__ loss_acc)     // [1] f32 (ws)
{
  __shared__ float lsum[4];
  const int tid  = threadIdx.x;
  const int wid  = tid >> 6;
  const int lane = tid & 63;
  const int row0 = blockIdx.x * 16 + wid * 4;

  const float* xr0 = x + (size_t)row0 * CC;
  float acc[4] = {0.f, 0.f, 0.f, 0.f};
  #pragma unroll 4
  for (int c0 = 0; c0 < CC; c0 += 4) {
    float4 wv = *(const float4*)&wT4[(c0 << 6) + (lane << 2)];  // coalesced
    #pragma unroll
    for (int r = 0; r < 4; ++r) {
      float4 xv = *(const float4*)(xr0 + r * CC + c0);          // wave-uniform
      acc[r] += xv.x * wv.x + xv.y * wv.y + xv.z * wv.z + xv.w * wv.w;
    }
  }
  const float mb = map_b[lane];
  float kk[4] = {acc[0] + mb, acc[1] + mb, acc[2] + mb, acc[3] + mb};

  float ce[8], c2[8], lp[8];
  #pragma unroll
  for (int e = 0; e < 8; ++e) {
    ce[e] = cent[e * RDIM + lane];
    float v = ce[e] * ce[e];
    #pragma unroll
    for (int off = 32; off; off >>= 1) v += __shfl_xor(v, off, 64);
    c2[e] = v;
    lp[e] = __logf(prior[e]);
  }

  float dsum = 0.f;
  #pragma unroll
  for (int r = 0; r < 4; ++r) {
    float k = kk[r];
    float v[9];
    v[0] = k * k;
    #pragma unroll
    for (int e = 0; e < 8; ++e) v[e + 1] = k * ce[e];
    #pragma unroll
    for (int off = 32; off; off >>= 1) {
      #pragma unroll
      for (int q = 0; q < 9; ++q) v[q] += __shfl_xor(v[q], off, 64);
    }
    float lr[8], mx = -3.4e38f;
    #pragma unroll
    for (int e = 0; e < 8; ++e) {
      float d2 = v[0] + c2[e] - 2.f * v[e + 1];
      lr[e] = -0.5f * d2 - LOG2PI_TERM + lp[e];
      mx = fmaxf(mx, lr[e]);
    }
    float s = 0.f;
    #pragma unroll
    for (int e = 0; e < 8; ++e) s += __expf(lr[e] - mx);
    float denom = mx + __logf(s);
    dsum += denom;
    float myv = 0.f;
    #pragma unroll
    for (int e = 0; e < 8; ++e) {
      float re = __expf(lr[e] - denom);
      myv = (lane == e) ? re : myv;
    }
    if (lane < 8) resp_out[(size_t)(row0 + r) * NE + lane] = myv;
  }
  if (lane == 0) lsum[wid] = dsum;
  __syncthreads();
  if (tid == 0) {
    float t = lsum[0] + lsum[1] + lsum[2] + lsum[3];
    atomicAdd(loss_acc, -COMMIT_SCALE * t);
  }
}

// ---------------------------------------------------------------------------
// Kernel 2: y[m,o] = sum_e sum_k (resp[m,e]*x[m,k]) * W_e[o,k] + bias_b[o].
// 64x128 tile, 1024 blocks (4/CU). Per wave: 32x64 = 2x4 frags of 16x16x32.
// A (64x32) packed from f32 x with resp fused, static 1-deep prefetch;
// B (128x32) via global_load_lds w/ double-XOR swizzle. 2 barriers/iter.
// ---------------------------------------------------------------------------
__global__ __launch_bounds__(256, 4) void k_moe(
    const float* __restrict__ x,             // [N, C] f32
    const unsigned short* __restrict__ wb,   // [9, O, C] bf16 (ws)
    const float* __restrict__ bb,            // [O] f32
    const float* __restrict__ resp,          // [N, NE] f32 (ws)
    const float* __restrict__ loss_acc,      // [1] f32 (ws)
    float* __restrict__ out)                 // [N*O + 1] f32
{
  __shared__ unsigned short aT[64 * 40];     // A: 64 rows, padded stride 40
  __shared__ unsigned short bT[128 * 32];    // B: 128 rows, unpadded (gl_lds)
  __shared__ float sc[NEXP * 64];

  const int tid = threadIdx.x;
  const int m0 = blockIdx.x * 64;
  const int o0 = blockIdx.y * 128;

  // resp scales: sc[e][row]; expert 8 (bias_w) = 1.0
  for (int idx = tid; idx < 64 * NE; idx += 256) {
    int r = idx >> 3, e = idx & 7;
    sc[e * 64 + r] = resp[(size_t)(m0 + r) * NE + e];
  }
  if (tid < 64) sc[8 * 64 + tid] = 1.0f;

  const int lane = tid & 63;
  const int wid = tid >> 6;
  const int wm = (wid & 1) * 32;        // wave M offset (0/32)
  const int wn = (wid >> 1) * 64;       // wave O offset (0/64)
  const int fr = lane & 15;
  const int fq = lane >> 4;

  // A staging: 64 rows x 32 k; thread -> row tid>>2, 8 k at (tid&3)*8
  const int srow = tid >> 2;
  const int scol = (tid & 3) * 8;
  const float4* xr4 = (const float4*)(x + (size_t)(m0 + srow) * CC + scol);

  // B staging via gl_lds: wave stages rows wid*32..+31 (2 calls of 16 rows);
  // lane l -> row l>>2, LDS chunk pos l&3, fetches global chunk (l&3)^swz(row)
  const int srB = lane >> 2;
  const int gchunk = (lane & 3) ^ (srB & 3) ^ ((srB >> 2) & 3);
  const size_t b_go = (size_t)(o0 + wid * 32 + srB) * CC + gchunk * 8;
  const unsigned short* wbp = wb + b_go;
  const size_t row16 = (size_t)16 * CC;
  unsigned short* b_l0 = bT + wid * 1024;
  unsigned short* b_l1 = b_l0 + 512;
  const int rchunkB = (fq ^ (fr & 3) ^ ((fr >> 2) & 3)) * 8;

  f32x4 zero4 = {0.f, 0.f, 0.f, 0.f};
  f32x4 acc[2][4];
  #pragma unroll
  for (int i = 0; i < 2; ++i)
    #pragma unroll
    for (int j = 0; j < 4; ++j) acc[i][j] = zero4;

  __syncthreads();   // sc visible

  // static-register prefetch of x chunk 0 (8 floats/thread)
  float4 pA = xr4[0];
  float4 pB = xr4[1];

  for (int e = 0; e < NEXP; ++e) {
    const unsigned short* Bb = wbp + (size_t)e * (OO * CC);
    const float s = sc[e * 64 + srow];

    for (int kk = 0; kk < 16; ++kk) {
      __syncthreads();   // previous iteration's LDS readers done
      gl_lds16(Bb + kk * 32,         b_l0);
      gl_lds16(Bb + kk * 32 + row16, b_l1);
      // pack current chunk from prefetched regs (ready since last barrier)
      uint4 w;
      w.x = pkt(pA.x * s, pA.y * s);
      w.y = pkt(pA.z * s, pA.w * s);
      w.z = pkt(pB.x * s, pB.y * s);
      w.w = pkt(pB.z * s, pB.w * s);
      *(uint4*)&aT[srow * 40 + scol] = w;
      // prefetch next chunk (static regs; latency overlaps barrier drain)
      const int nk = (kk + 1) & 15;
      pA = xr4[nk * 8];
      pB = xr4[nk * 8 + 1];
      __syncthreads();   // drains gl_lds + ds_write (and prefetch issue is async)

      short8 af[2], bfr[4];
      #pragma unroll
      for (int i = 0; i < 2; ++i)
        af[i] = *(const short8*)&aT[(wm + i * 16 + fr) * 40 + fq * 8];
      #pragma unroll
      for (int j = 0; j < 4; ++j)
        bfr[j] = *(const short8*)&bT[(wn + j * 16 + fr) * 32 + rchunkB];

      #pragma unroll
      for (int i = 0; i < 2; ++i)
        #pragma unroll
        for (int j = 0; j < 4; ++j)
          acc[i][j] = __builtin_amdgcn_mfma_f32_16x16x32_bf16(af[i], bfr[j], acc[i][j], 0, 0, 0);
    }
  }

  // epilogue: + bias_b, store f32
  #pragma unroll
  for (int j = 0; j < 4; ++j) {
    const int o = o0 + wn + j * 16 + fr;
    const float bias = bb[o];
    #pragma unroll
    for (int i = 0; i < 2; ++i) {
      #pragma unroll
      for (int r = 0; r < 4; ++r) {
        int m = m0 + wm + i * 16 + fq * 4 + r;
        out[(size_t)m * OO + o] = acc[i][j][r] + bias;
      }
    }
  }

  if (blockIdx.x == 0 && blockIdx.y == 0 && tid == 0)
    out[(size_t)NROWS * OO] = loss_acc[0];
}

extern "C" void kernel_launch(void* const* d_in, const int* in_sizes, int n_in,
                              void* d_out, int out_size, void* d_ws, size_t ws_size,
                              hipStream_t stream) {
  const float* x     = (const float*)d_in[0];
  // d_in[1] = key_feat (ignored by forward)
  const float* map_w = (const float*)d_in[2];
  const float* map_b = (const float*)d_in[3];
  const float* cent  = (const float*)d_in[4];
  const float* prior = (const float*)d_in[5];
  const float* pw    = (const float*)d_in[6];
  const float* bw    = (const float*)d_in[7];
  const float* bb    = (const float*)d_in[8];
  float* out = (float*)d_out;

  char* wsp = (char*)d_ws;
  float* resp = (float*)wsp;                              // 524288 B
  float* loss = (float*)(wsp + 524288);                   // 16 B slot
  unsigned short* wb = (unsigned short*)(wsp + 524304);   // 4718592 B
  float* wT4 = (float*)(wsp + 524304 + 4718592);          // 131072 B

  hipMemsetAsync(loss, 0, sizeof(float), stream);
  k_prep<<<dim3(NCV + TB), dim3(256), 0, stream>>>(pw, bw, map_w, wb, wT4);
  k_assign<<<dim3(NROWS / 16), dim3(256), 0, stream>>>(x, wT4, map_b, cent, prior, resp, loss);
  dim3 grid(NROWS / 64, OO / 128);
  k_moe<<<grid, dim3(256), 0, stream>>>(x, wb, bb, resp, loss, out);
}

// Round 7
// 313.874 us; speedup vs baseline: 1.8609x; 1.1747x over previous
//
#include <hip/hip_runtime.h>
#include <hip/hip_bf16.h>

// Problem constants (T=2048, B=8, C=512, O=512, RD=64, NE=8, tau=1, commit=0.1)
// All I/O float32. Single fused GEMM over K'=9*512: resp folded into A at
// staging (bf16). Round-7: single-barrier software pipeline — kk-outer /
// e-inner loop, B[it+1] gl_lds + A[it+1] pack issued right AFTER the barrier
// so every drain sees ops aged by a full MFMA block (round-4/6 issued B
// immediately before the draining barrier -> full L2 latency exposed/iter).
// A dbuf stride-40 (2-way, free), B dbuf unpadded w/ double-XOR swizzle
// (2-way, free; round-4 single-XOR was 4-way).
#define NROWS 16384
#define CC 512
#define OO 512
#define RDIM 64
#define NE 8
#define NEXP 9            // 8 experts + bias_w as expert 8 (scale 1.0)
#define COMMIT_SCALE 0.1f
#define LOG2PI_TERM 58.81206612509905f   // (RD/2)*log(2*pi*tau), tau=1

typedef __attribute__((ext_vector_type(8))) short short8;
typedef __attribute__((ext_vector_type(4))) float f32x4;

__device__ __forceinline__ unsigned short f2bf(float f) {
  unsigned int u = __float_as_uint(f);
  u += 0x7fffu + ((u >> 16) & 1u);   // round-to-nearest-even
  return (unsigned short)(u >> 16);
}
// truncating pack: [hi16(b) | hi16(a)] — 1 ulp worse than RNE; threshold 3788
__device__ __forceinline__ unsigned int pkt(float a, float b) {
  return (__float_as_uint(b) & 0xffff0000u) | (__float_as_uint(a) >> 16);
}

__device__ __forceinline__ void gl_lds16(const unsigned short* g, unsigned short* l) {
  __builtin_amdgcn_global_load_lds(
      (const __attribute__((address_space(1))) void*)g,
      (__attribute__((address_space(3))) void*)l, 16, 0, 0);
}

// ---------------------------------------------------------------------------
// Kernel 0: f32->bf16 copy of [pw_w ; bias_w] -> wb; transpose map_w -> wT4.
// ---------------------------------------------------------------------------
#define P4 524288u    // pw_w float4 count   (2097152 / 4)
#define B4 65536u     // bias_w float4 count (262144 / 4)
#define NCV ((P4 + B4) / 256u)        // 2304 convert blocks
#define TB 128u                        // 32768 map_w elems / 256

__global__ __launch_bounds__(256) void k_prep(
    const float* __restrict__ pw, const float* __restrict__ bw,
    const float* __restrict__ mw,
    unsigned short* __restrict__ wb, float* __restrict__ wT4)
{
  unsigned int b = blockIdx.x;
  if (b >= NCV) {   // map_w transpose: i indexes map_w[j*512+c]
    unsigned int i = (b - NCV) * 256 + threadIdx.x;
    unsigned int j = i >> 9, c = i & 511u;
    wT4[((c >> 2) << 8) + (j << 2) + (c & 3u)] = mw[i];
    return;
  }
  unsigned int i = b * 256 + threadIdx.x;   // float4 index into [pw|bw]
  const float* src = (i < P4) ? (pw + (size_t)i * 4)
                              : (bw + (size_t)(i - P4) * 4);
  unsigned short* dst = wb + (size_t)i * 4;
  float4 v = *(const float4*)src;
  ushort4 o;
  o.x = f2bf(v.x); o.y = f2bf(v.y); o.z = f2bf(v.z); o.w = f2bf(v.w);
  *(ushort4*)dst = o;
}

// ---------------------------------------------------------------------------
// Kernel 1: GMM responsibilities + loss (pure f32).
// ---------------------------------------------------------------------------
__global__ __launch_bounds__(256) void k_assign(
    const float* __restrict__ x,      // [N, C]
    const float* __restrict__ wT4,    // [C/4, 64, 4] transposed map_w
    const float* __restrict__ map_b,  // [RD]
    const float* __restrict__ cent,   // [NE, RD]
    const float* __restrict__ prior,  // [NE]
    float* __restrict__ resp_out,     // [N, NE] f32 (ws)
    float* __restrict__ loss_acc)     // [1] f32 (ws)
{
  __shared__ float lsum[4];
  const int tid  = threadIdx.x;
  const int wid  = tid >> 6;
  const int lane = tid & 63;
  const int row0 = blockIdx.x * 16 + wid * 4;

  const float* xr0 = x + (size_t)row0 * CC;
  float acc[4] = {0.f, 0.f, 0.f, 0.f};
  #pragma unroll 4
  for (int c0 = 0; c0 < CC; c0 += 4) {
    float4 wv = *(const float4*)&wT4[(c0 << 6) + (lane << 2)];  // coalesced
    #pragma unroll
    for (int r = 0; r < 4; ++r) {
      float4 xv = *(const float4*)(xr0 + r * CC + c0);          // wave-uniform
      acc[r] += xv.x * wv.x + xv.y * wv.y + xv.z * wv.z + xv.w * wv.w;
    }
  }
  const float mb = map_b[lane];
  float kk[4] = {acc[0] + mb, acc[1] + mb, acc[2] + mb, acc[3] + mb};

  float ce[8], c2[8], lp[8];
  #pragma unroll
  for (int e = 0; e < 8; ++e) {
    ce[e] = cent[e * RDIM + lane];
    float v = ce[e] * ce[e];
    #pragma unroll
    for (int off = 32; off; off >>= 1) v += __shfl_xor(v, off, 64);
    c2[e] = v;
    lp[e] = __logf(prior[e]);
  }

  float dsum = 0.f;
  #pragma unroll
  for (int r = 0; r < 4; ++r) {
    float k = kk[r];
    float v[9];
    v[0] = k * k;
    #pragma unroll
    for (int e = 0; e < 8; ++e) v[e + 1] = k * ce[e];
    #pragma unroll
    for (int off = 32; off; off >>= 1) {
      #pragma unroll
      for (int q = 0; q < 9; ++q) v[q] += __shfl_xor(v[q], off, 64);
    }
    float lr[8], mx = -3.4e38f;
    #pragma unroll
    for (int e = 0; e < 8; ++e) {
      float d2 = v[0] + c2[e] - 2.f * v[e + 1];
      lr[e] = -0.5f * d2 - LOG2PI_TERM + lp[e];
      mx = fmaxf(mx, lr[e]);
    }
    float s = 0.f;
    #pragma unroll
    for (int e = 0; e < 8; ++e) s += __expf(lr[e] - mx);
    float denom = mx + __logf(s);
    dsum += denom;
    float myv = 0.f;
    #pragma unroll
    for (int e = 0; e < 8; ++e) {
      float re = __expf(lr[e] - denom);
      myv = (lane == e) ? re : myv;
    }
    if (lane < 8) resp_out[(size_t)(row0 + r) * NE + lane] = myv;
  }
  if (lane == 0) lsum[wid] = dsum;
  __syncthreads();
  if (tid == 0) {
    float t = lsum[0] + lsum[1] + lsum[2] + lsum[3];
    atomicAdd(loss_acc, -COMMIT_SCALE * t);
  }
}

// ---------------------------------------------------------------------------
// Kernel 2: y[m,o] = sum_e sum_k (resp[m,e]*x[m,k]) * W_e[o,k] + bias_b[o].
// 128x128 tile, BK=32, kk-outer/e-inner. ONE barrier per iteration; B[it+1]
// gl_lds and A[it+1] ds_write issued right after it (aged a full iteration
// at the next drain). x chunk register-resident across the 9 experts.
// ---------------------------------------------------------------------------
__global__ __launch_bounds__(256, 2) void k_moe(
    const float* __restrict__ x,             // [N, C] f32
    const unsigned short* __restrict__ wb,   // [9, O, C] bf16 (ws)
    const float* __restrict__ bb,            // [O] f32
    const float* __restrict__ resp,          // [N, NE] f32 (ws)
    const float* __restrict__ loss_acc,      // [1] f32 (ws)
    float* __restrict__ out)                 // [N*O + 1] f32
{
  __shared__ unsigned short aT[2][128 * 40];   // A dbuf, padded stride 40
  __shared__ unsigned short bT[2][128 * 32];   // B dbuf, unpadded (gl_lds)
  __shared__ float sc[NEXP * 128];

  const int tid = threadIdx.x;
  const int m0 = blockIdx.x * 128;
  const int o0 = blockIdx.y * 128;

  // resp scales: sc[e][row]; expert 8 (bias_w) = 1.0
  for (int idx = tid; idx < 128 * NE; idx += 256) {
    int r = idx >> 3, e = idx & 7;
    sc[e * 128 + r] = resp[(size_t)(m0 + r) * NE + e];
  }
  if (tid < 128) sc[8 * 128 + tid] = 1.0f;

  const int lane = tid & 63;
  const int wid = tid >> 6;
  const int wm = (wid & 1) * 64;
  const int wn = (wid >> 1) * 64;
  const int fr = lane & 15;
  const int fq = lane >> 4;

  // A staging: thread -> row tid>>1, 16 k at (tid&1)*16 (2 lanes/row: 2-way)
  const int srow = tid >> 1;
  const int scol = (tid & 1) * 16;
  const float4* xb4 = (const float4*)(x + (size_t)(m0 + srow) * CC) + (tid & 1) * 4;

  // B staging via gl_lds: lane l -> row l>>2, LDS chunk pos l&3, fetches
  // global chunk (l&3)^swz(row), swz(r)=(r&3)^((r>>2)&3)  (2-way on read)
  const int srB = lane >> 2;
  const int gch = (lane & 3) ^ (srB & 3) ^ ((srB >> 2) & 3);
  const size_t b_go = (size_t)(o0 + wid * 32 + srB) * CC + gch * 8;
  const unsigned short* wbp = wb + b_go;
  const size_t row16 = (size_t)16 * CC;
  const int ldsB = wid * 1024;
  const int rchB = (fq ^ (fr & 3) ^ ((fr >> 2) & 3)) * 8;

  f32x4 zero4 = {0.f, 0.f, 0.f, 0.f};
  f32x4 acc[4][4];
  #pragma unroll
  for (int i = 0; i < 4; ++i)
    #pragma unroll
    for (int j = 0; j < 4; ++j) acc[i][j] = zero4;

  __syncthreads();   // sc visible

  // x chunk 0 -> cx (used now), chunk 1 -> pX (used at kk wrap)
  float4 cx0 = xb4[0], cx1 = xb4[1], cx2 = xb4[2], cx3 = xb4[3];
  float4 pX0 = xb4[8], pX1 = xb4[9], pX2 = xb4[10], pX3 = xb4[11];

  // prologue: pack A(kk=0,e=0) -> aT[0]; gl_lds B(kk=0,e=0) -> bT[0]
  {
    const float s = sc[srow];
    uint4 w0, w1;
    w0.x = pkt(cx0.x * s, cx0.y * s); w0.y = pkt(cx0.z * s, cx0.w * s);
    w0.z = pkt(cx1.x * s, cx1.y * s); w0.w = pkt(cx1.z * s, cx1.w * s);
    w1.x = pkt(cx2.x * s, cx2.y * s); w1.y = pkt(cx2.z * s, cx2.w * s);
    w1.z = pkt(cx3.x * s, cx3.y * s); w1.w = pkt(cx3.z * s, cx3.w * s);
    *(uint4*)&aT[0][srow * 40 + scol]     = w0;
    *(uint4*)&aT[0][srow * 40 + scol + 8] = w1;
  }
  gl_lds16(wbp,         &bT[0][ldsB]);
  gl_lds16(wbp + row16, &bT[0][ldsB + 512]);

  int cur = 0;
  for (int kk = 0; kk < 16; ++kk) {
    for (int e = 0; e < NEXP; ++e) {
      const int nxt = cur ^ 1;
      __syncthreads();   // A[cur],B[cur] complete; it-1 readers of [nxt] done

      // stage NEXT iteration (aged a full MFMA block at the next drain)
      if (e < 8) {
        const unsigned short* bn = wbp + ((size_t)(e + 1) << 18) + kk * 32;
        gl_lds16(bn,         &bT[nxt][ldsB]);
        gl_lds16(bn + row16, &bT[nxt][ldsB + 512]);
        const float s = sc[(e + 1) * 128 + srow];
        uint4 w0, w1;
        w0.x = pkt(cx0.x * s, cx0.y * s); w0.y = pkt(cx0.z * s, cx0.w * s);
        w0.z = pkt(cx1.x * s, cx1.y * s); w0.w = pkt(cx1.z * s, cx1.w * s);
        w1.x = pkt(cx2.x * s, cx2.y * s); w1.y = pkt(cx2.z * s, cx2.w * s);
        w1.z = pkt(cx3.x * s, cx3.y * s); w1.w = pkt(cx3.z * s, cx3.w * s);
        *(uint4*)&aT[nxt][srow * 40 + scol]     = w0;
        *(uint4*)&aT[nxt][srow * 40 + scol + 8] = w1;
      } else if (kk < 15) {
        const unsigned short* bn = wbp + (kk + 1) * 32;
        gl_lds16(bn,         &bT[nxt][ldsB]);
        gl_lds16(bn + row16, &bT[nxt][ldsB + 512]);
        const float s = sc[srow];
        uint4 w0, w1;
        w0.x = pkt(pX0.x * s, pX0.y * s); w0.y = pkt(pX0.z * s, pX0.w * s);
        w0.z = pkt(pX1.x * s, pX1.y * s); w0.w = pkt(pX1.z * s, pX1.w * s);
        w1.x = pkt(pX2.x * s, pX2.y * s); w1.y = pkt(pX2.z * s, pX2.w * s);
        w1.z = pkt(pX3.x * s, pX3.y * s); w1.w = pkt(pX3.z * s, pX3.w * s);
        *(uint4*)&aT[nxt][srow * 40 + scol]     = w0;
        *(uint4*)&aT[nxt][srow * 40 + scol + 8] = w1;
        // rotate x regs; prefetch kk+2 (lands within the next 9 iterations)
        cx0 = pX0; cx1 = pX1; cx2 = pX2; cx3 = pX3;
        if (kk < 14) {
          const int nk = (kk + 2) * 8;
          pX0 = xb4[nk];     pX1 = xb4[nk + 1];
          pX2 = xb4[nk + 2]; pX3 = xb4[nk + 3];
        }
      }

      // compute current iteration
      short8 af[4], bfr[4];
      #pragma unroll
      for (int i = 0; i < 4; ++i)
        af[i] = *(const short8*)&aT[cur][(wm + i * 16 + fr) * 40 + fq * 8];
      #pragma unroll
      for (int j = 0; j < 4; ++j)
        bfr[j] = *(const short8*)&bT[cur][(wn + j * 16 + fr) * 32 + rchB];

      #pragma unroll
      for (int i = 0; i < 4; ++i)
        #pragma unroll
        for (int j = 0; j < 4; ++j)
          acc[i][j] = __builtin_amdgcn_mfma_f32_16x16x32_bf16(af[i], bfr[j], acc[i][j], 0, 0, 0);

      cur = nxt;
    }
  }

  // epilogue: + bias_b, store f32
  #pragma unroll
  for (int j = 0; j < 4; ++j) {
    const int o = o0 + wn + j * 16 + fr;
    const float bias = bb[o];
    #pragma unroll
    for (int i = 0; i < 4; ++i) {
      #pragma unroll
      for (int r = 0; r < 4; ++r) {
        int m = m0 + wm + i * 16 + fq * 4 + r;
        out[(size_t)m * OO + o] = acc[i][j][r] + bias;
      }
    }
  }

  if (blockIdx.x == 0 && blockIdx.y == 0 && tid == 0)
    out[(size_t)NROWS * OO] = loss_acc[0];
}

extern "C" void kernel_launch(void* const* d_in, const int* in_sizes, int n_in,
                              void* d_out, int out_size, void* d_ws, size_t ws_size,
                              hipStream_t stream) {
  const float* x     = (const float*)d_in[0];
  // d_in[1] = key_feat (ignored by forward)
  const float* map_w = (const float*)d_in[2];
  const float* map_b = (const float*)d_in[3];
  const float* cent  = (const float*)d_in[4];
  const float* prior = (const float*)d_in[5];
  const float* pw    = (const float*)d_in[6];
  const float* bw    = (const float*)d_in[7];
  const float* bb    = (const float*)d_in[8];
  float* out = (float*)d_out;

  char* wsp = (char*)d_ws;
  float* resp = (float*)wsp;                              // 524288 B
  float* loss = (float*)(wsp + 524288);                   // 16 B slot
  unsigned short* wb = (unsigned short*)(wsp + 524304);   // 4718592 B
  float* wT4 = (float*)(wsp + 524304 + 4718592);          // 131072 B

  hipMemsetAsync(loss, 0, sizeof(float), stream);
  k_prep<<<dim3(NCV + TB), dim3(256), 0, stream>>>(pw, bw, map_w, wb, wT4);
  k_assign<<<dim3(NROWS / 16), dim3(256), 0, stream>>>(x, wT4, map_b, cent, prior, resp, loss);
  dim3 grid(NROWS / 128, OO / 128);
  k_moe<<<grid, dim3(256), 0, stream>>>(x, wb, bb, resp, loss, out);
}